// Round 10
// baseline (362.426 us; speedup 1.0000x reference)
//
#include <hip/hip_runtime.h>
#include <hip/hip_bf16.h>

// GraphSAGE backbone: 2x SAGEConv(mean), N=100000, E=1600000, D=128, fp32 in/out.
// CSR build via 2-pass bucket binning. Feature matrices stored SLICED:
//   buf[s][node][16 bf16]  (s = col/16, 8 slices of 32 B)
// so the per-XCD aggregation working set (3.2 MB) fits the 4-MB private L2.
// Aggregation: one block per (slice = bid%8 -> XCD, 16-node chunk); per-edge
// gather is an L2-hit. csr read non-temporally to avoid polluting L2.
// GEMM: fused relu(agg@Wl + h@Wr + b), bf16 MFMA, fragment-major weights, no LDS.

#define D 128
#define WSTRIDE 136            // fallback path only
#define WPANEL (D * WSTRIDE)
#define GCAP 12288             // per-bucket capacity (mean ~8166)

typedef __attribute__((ext_vector_type(8))) short short8v;
typedef __attribute__((ext_vector_type(4))) float f32x4;
typedef __attribute__((ext_vector_type(4))) unsigned int u32x4;

__device__ inline unsigned short f2bf(float f) {   // fp32 -> bf16 RNE
  unsigned u = __float_as_uint(f);
  return (unsigned short)((u + 0x7FFFu + ((u >> 16) & 1u)) >> 16);
}
__device__ inline unsigned pack2(float lo, float hi) {
  return (unsigned)f2bf(lo) | ((unsigned)f2bf(hi) << 16);
}

// acc += lo_bf16(u) : src1 = {1.0bf16, 0} = 0x00003F80 (SGPR)
__device__ inline void dot2lo(unsigned u, float& a) {
  asm("v_dot2_f32_bf16 %0, %1, %2, %0" : "+v"(a) : "v"(u), "s"(0x00003F80u));
}
// acc += hi_bf16(u) : src1 = {0, 1.0bf16} = 0x3F800000 = inline const 1.0
__device__ inline void dot2hi(unsigned u, float& a) {
  asm("v_dot2_f32_bf16 %0, %1, 1.0, %0" : "+v"(a) : "v"(u));
}

// ---- pass A: bin edges by dst>>9 into gbuf[b*GCAP + cursor] ---------------

__global__ __launch_bounds__(256) void k_bin(const int* __restrict__ ei, int E,
                                             int* __restrict__ gcur,
                                             int* __restrict__ gbuf) {
  __shared__ int hcnt[256], hbase[256], hfill[256];
  int tid = threadIdx.x;
  hcnt[tid] = 0;
  __syncthreads();
  int ent[8], bk[8];
#pragma unroll
  for (int it = 0; it < 8; ++it) {
    int e = blockIdx.x * 2048 + it * 256 + tid;
    if (e < E) {
      int s = ei[e], d = ei[E + e];
      bk[it] = d >> 9;
      ent[it] = (s << 9) | (d & 511);
      atomicAdd(&hcnt[bk[it]], 1);
    } else bk[it] = -1;
  }
  __syncthreads();
  int c = hcnt[tid];
  hbase[tid] = c ? atomicAdd(&gcur[tid], c) : 0;
  hfill[tid] = 0;
  __syncthreads();
#pragma unroll
  for (int it = 0; it < 8; ++it) {
    if (bk[it] >= 0) {
      int slot = atomicAdd(&hfill[bk[it]], 1);
      gbuf[(size_t)bk[it] * GCAP + hbase[bk[it]] + slot] = ent[it];
    }
  }
}

// ---- pass B1: per-bucket degree histogram -> cnt (coalesced) ---------------

__global__ __launch_bounds__(256) void k_hist(const int* __restrict__ gcur,
                                              const int* __restrict__ gbuf,
                                              int* __restrict__ cnt, int n) {
  __shared__ int hc[512];
  int b = blockIdx.x, tid = threadIdx.x;
  hc[tid] = 0; hc[tid + 256] = 0;
  __syncthreads();
  int m = gcur[b];
  for (int i = tid; i < m; i += 256)
    atomicAdd(&hc[gbuf[(size_t)b * GCAP + i] & 511], 1);
  __syncthreads();
#pragma unroll
  for (int k = 0; k < 2; ++k) {
    int i = k * 256 + tid, node = b * 512 + i;
    if (node < n) cnt[node] = hc[i];
  }
}

// ---- hierarchical exclusive scan: cnt -> rowptr, plus inv_denom ------------

__global__ __launch_bounds__(1024) void k_scan1(const int* __restrict__ cnt, int n,
                                                int* __restrict__ rowptr,
                                                float* __restrict__ inv_denom,
                                                int* __restrict__ bsum) {
  __shared__ int wsum[16];
  int tid = threadIdx.x, lane = tid & 63, wid = tid >> 6;
  int i = blockIdx.x * 1024 + tid;
  int v = (i < n) ? cnt[i] : 0;
  int x = v;
#pragma unroll
  for (int off = 1; off < 64; off <<= 1) {
    int t = __shfl_up(x, (unsigned)off);
    if (lane >= off) x += t;
  }
  if (lane == 63) wsum[wid] = x;
  __syncthreads();
  if (tid < 16) {
    int w = wsum[tid], y = w;
#pragma unroll
    for (int off = 1; off < 16; off <<= 1) {
      int t = __shfl_up(y, (unsigned)off);
      if (tid >= off) y += t;
    }
    wsum[tid] = y - w;   // exclusive
  }
  __syncthreads();
  if (i < n) {
    rowptr[i] = wsum[wid] + x - v;
    inv_denom[i] = 1.0f / (float)((v > 1) ? v : 1);
  }
  if (tid == 1023) bsum[blockIdx.x] = wsum[15] + x;
}

__global__ __launch_bounds__(64) void k_scan2(int* __restrict__ bsum, int nb,
                                              int* __restrict__ rowptr, int n) {
  int lane = threadIdx.x;
  int v0 = (lane < nb) ? bsum[lane] : 0;
  int v1 = (64 + lane < nb) ? bsum[64 + lane] : 0;
  int x = v0;
#pragma unroll
  for (int off = 1; off < 64; off <<= 1) {
    int t = __shfl_up(x, (unsigned)off);
    if (lane >= off) x += t;
  }
  int tot0 = __shfl(x, 63);
  int y = v1;
#pragma unroll
  for (int off = 1; off < 64; off <<= 1) {
    int t = __shfl_up(y, (unsigned)off);
    if (lane >= off) y += t;
  }
  if (lane < nb) bsum[lane] = x - v0;
  if (64 + lane < nb) bsum[64 + lane] = tot0 + (y - v1);
  if (lane == 63) rowptr[n] = tot0 + y;
}

__global__ __launch_bounds__(1024) void k_scan3(int* __restrict__ rowptr,
                                                const int* __restrict__ bsum, int n) {
  int i = blockIdx.x * 1024 + threadIdx.x;
  if (i < n) rowptr[i] += bsum[blockIdx.x];
}

// ---- pass B2: place entries into csr (one bucket = one block) --------------

__global__ __launch_bounds__(256) void k_place(const int* __restrict__ gcur,
                                               const int* __restrict__ gbuf,
                                               const int* __restrict__ rowptr,
                                               int* __restrict__ csr, int n) {
  __shared__ int rp[512], hf[512];
  int b = blockIdx.x, tid = threadIdx.x;
#pragma unroll
  for (int k = 0; k < 2; ++k) {
    int i = k * 256 + tid, node = b * 512 + i;
    rp[i] = (node < n) ? rowptr[node] : 0;
    hf[i] = 0;
  }
  __syncthreads();
  int m = gcur[b];
  for (int i = tid; i < m; i += 256) {
    int ent = gbuf[(size_t)b * GCAP + i];
    int d = ent & 511, s = ent >> 9;
    csr[rp[d] + atomicAdd(&hf[d], 1)] = s;
  }
}

// ---- fp32 x -> bf16 SLICED layout (full-line coalesced stores) -------------

__global__ __launch_bounds__(256) void k_tobf16_sl(const float* __restrict__ in,
                                                   short* __restrict__ ob,
                                                   int n, int np) {
  int id = blockIdx.x * 256 + threadIdx.x;
  if (id >= n * 16) return;
  int node = id >> 4, ch = id & 15;
  const float4* p = (const float4*)(in + (size_t)node * D + ch * 8);
  float4 a = p[0], b = p[1];
  u32x4 o;
  o.x = pack2(a.x, a.y); o.y = pack2(a.z, a.w);
  o.z = pack2(b.x, b.y); o.w = pack2(b.z, b.w);
  __builtin_nontemporal_store(
      o, (u32x4*)(ob + ((size_t)(ch >> 1) * np + node) * 16 + (ch & 1) * 8));
}

// ---- weight prep (fragment-major): WF[((t*8+cc)*64+l)*8+j] =
//        bf16( W[t*32 + (l>>4)*8 + j][cc*16 + (l&15)] )  -------------------

__global__ __launch_bounds__(256) void k_wprep_frag(const float* __restrict__ W0,
                                                    const float* __restrict__ W1,
                                                    const float* __restrict__ W2,
                                                    const float* __restrict__ W3,
                                                    short* __restrict__ WF) {
  const float* W = (blockIdx.y == 0) ? W0 : (blockIdx.y == 1) ? W1
                 : (blockIdx.y == 2) ? W2 : W3;
  short* o = WF + (size_t)blockIdx.y * (D * D);
  int i = blockIdx.x * 256 + threadIdx.x;
  if (i < D * D) {
    int j = i & 7, l = (i >> 3) & 63, cc = (i >> 9) & 7, t = i >> 12;
    int k = t * 32 + (l >> 4) * 8 + j;
    int c = cc * 16 + (l & 15);
    o[i] = (short)f2bf(W[k * D + c]);
  }
}

// ---- weight prep (padded-transpose, fallback path only) --------------------

__global__ __launch_bounds__(256) void k_wprep(const float* __restrict__ W0,
                                               const float* __restrict__ W1,
                                               const float* __restrict__ W2,
                                               const float* __restrict__ W3,
                                               short* __restrict__ WT) {
  const float* W = (blockIdx.y == 0) ? W0 : (blockIdx.y == 1) ? W1
                 : (blockIdx.y == 2) ? W2 : W3;
  short* o = WT + (size_t)blockIdx.y * WPANEL;
  int i = blockIdx.x * 256 + threadIdx.x;
  if (i < D * D) {
    int k = i >> 7, c = i & 127;
    o[c * WSTRIDE + k] = (short)f2bf(W[i]);
  }
}

// ---- SLICED mean aggregation -----------------------------------------------
// block -> slice s = bid%8 (XCD-pinned by round-robin dispatch), 16-node chunk.
// 16-lane quarter owns one node: l = (eoff = l>>1, half = l&1);
// 8 edges in flight, 2-deep -> 16 B L2-hit gather per lane.

__global__ __launch_bounds__(256) void k_agg_sl(const short* __restrict__ hb,
                                                const int* __restrict__ rowptr,
                                                const int* __restrict__ csr,
                                                const float* __restrict__ inv_denom,
                                                short* __restrict__ agg,
                                                int n, int np) {
  int b = blockIdx.x;
  int s = b & 7, chunk = b >> 3;
  int tid = threadIdx.x;
  int w = tid >> 6, lane = tid & 63;
  int q = lane >> 4, l = lane & 15;
  int eoff = l >> 1, half = l & 1;
  int nid = chunk * 16 + w * 4 + q;
  if (nid >= n) return;

  int beg = rowptr[nid], end = rowptr[nid + 1];
  const short* base = hb + (size_t)s * np * 16 + half * 8;

  float a[8];
#pragma unroll
  for (int k = 0; k < 8; ++k) a[k] = 0.f;
  auto addrow = [&](u32x4 v) {
    dot2lo(v.x, a[0]); dot2hi(v.x, a[1]);
    dot2lo(v.y, a[2]); dot2hi(v.y, a[3]);
    dot2lo(v.z, a[4]); dot2hi(v.z, a[5]);
    dot2lo(v.w, a[6]); dot2hi(v.w, a[7]);
  };

  int e = beg + eoff;
  for (; e + 8 < end; e += 16) {       // 2 rounds of 8 edges in flight
    int s0 = __builtin_nontemporal_load(csr + e);
    int s1 = __builtin_nontemporal_load(csr + e + 8);
    u32x4 v0 = *(const u32x4*)(base + (size_t)s0 * 16);
    u32x4 v1 = *(const u32x4*)(base + (size_t)s1 * 16);
    addrow(v0); addrow(v1);
  }
  if (e < end) {
    int s0 = __builtin_nontemporal_load(csr + e);
    u32x4 v0 = *(const u32x4*)(base + (size_t)s0 * 16);
    addrow(v0);
  }

#pragma unroll
  for (int k = 0; k < 8; ++k) {        // reduce across eoff (bits 1..3)
    a[k] += __shfl_xor(a[k], 2);
    a[k] += __shfl_xor(a[k], 4);
    a[k] += __shfl_xor(a[k], 8);
  }

  if (eoff == 0) {
    float iv = inv_denom[nid];
    u32x4 o;
    o.x = pack2(a[0] * iv, a[1] * iv);
    o.y = pack2(a[2] * iv, a[3] * iv);
    o.z = pack2(a[4] * iv, a[5] * iv);
    o.w = pack2(a[6] * iv, a[7] * iv);
    __builtin_nontemporal_store(
        o, (u32x4*)(agg + ((size_t)s * np + nid) * 16 + half * 8));
  }
}

// ---- fused layer GEMM, NO LDS, SLICED activations --------------------------
// Wave owns a 32-row tile; B-fragments fragment-major from L2.
// OUTF=0: bf16 SLICED out; OUTF=1: fp32 LINEAR out (d_out).

template <int OUTF>
__global__ __launch_bounds__(256) void k_fgemm_bf(const short* __restrict__ A,
                                                  const short* __restrict__ H,
                                                  const short* __restrict__ WFl,
                                                  const short* __restrict__ WFr,
                                                  const float* __restrict__ bias,
                                                  void* __restrict__ outv,
                                                  int n, int np) {
  int tid = threadIdx.x;
  int lane = tid & 63, w4 = tid >> 6;
  int nt = (n + 31) >> 5;
  int wtile = blockIdx.x * 4 + w4;
  if (wtile >= nt) return;
  int c = lane & 15, g = lane >> 4;
  int r0 = wtile * 32;
  int row0 = r0 + c, row1 = r0 + 16 + c;
  bool ok0 = row0 < n, ok1 = row1 < n;

  float bv[8];
#pragma unroll
  for (int cc = 0; cc < 8; ++cc) bv[cc] = bias[cc * 16 + c];

  const short8v* Fl = (const short8v*)WFl;
  const short8v* Fr = (const short8v*)WFr;

  f32x4 acc0[8], acc1[8];
#pragma unroll
  for (int cc = 0; cc < 8; ++cc) {
    acc0[cc] = (f32x4){0.f, 0.f, 0.f, 0.f};
    acc1[cc] = (f32x4){0.f, 0.f, 0.f, 0.f};
  }

#pragma unroll
  for (int t = 0; t < 4; ++t) {
    short8v a0 = (short8v){0,0,0,0,0,0,0,0}, h0 = a0, a1 = a0, h1 = a0;
    int kb = t * 32 + g * 8;
    size_t soff = (size_t)(kb >> 4) * np * 16 + (kb & 15);
    if (ok0) {
      a0 = *(const short8v*)(A + soff + (size_t)row0 * 16);
      h0 = *(const short8v*)(H + soff + (size_t)row0 * 16);
    }
    if (ok1) {
      a1 = *(const short8v*)(A + soff + (size_t)row1 * 16);
      h1 = *(const short8v*)(H + soff + (size_t)row1 * 16);
    }
#pragma unroll
    for (int cc = 0; cc < 8; ++cc) {
      short8v bl = Fl[(t * 8 + cc) * 64 + lane];
      short8v br = Fr[(t * 8 + cc) * 64 + lane];
      acc0[cc] = __builtin_amdgcn_mfma_f32_16x16x32_bf16(a0, bl, acc0[cc], 0, 0, 0);
      acc0[cc] = __builtin_amdgcn_mfma_f32_16x16x32_bf16(h0, br, acc0[cc], 0, 0, 0);
      acc1[cc] = __builtin_amdgcn_mfma_f32_16x16x32_bf16(a1, bl, acc1[cc], 0, 0, 0);
      acc1[cc] = __builtin_amdgcn_mfma_f32_16x16x32_bf16(h1, br, acc1[cc], 0, 0, 0);
    }
  }

#pragma unroll
  for (int cc = 0; cc < 8; ++cc) {
#pragma unroll
    for (int i = 0; i < 4; ++i) {
      int rr0 = r0 + g * 4 + i;
      int rr1 = rr0 + 16;
      float o0 = acc0[cc][i] + bv[cc];
      float o1 = acc1[cc][i] + bv[cc];
      o0 = o0 > 0.f ? o0 : 0.f;
      o1 = o1 > 0.f ? o1 : 0.f;
      if (OUTF) {
        if (rr0 < n) ((float*)outv)[(size_t)rr0 * D + cc * 16 + c] = o0;
        if (rr1 < n) ((float*)outv)[(size_t)rr1 * D + cc * 16 + c] = o1;
      } else {   // sliced bf16: col = cc*16+c -> slice cc, j = c
        if (rr0 < n)
          ((short*)outv)[((size_t)cc * np + rr0) * 16 + c] = (short)f2bf(o0);
        if (rr1 < n)
          ((short*)outv)[((size_t)cc * np + rr1) * 16 + c] = (short)f2bf(o1);
      }
    }
  }
}

// ---- fp32 fallback kernels (used only if ws_size is too small) -------------

__global__ __launch_bounds__(256) void k_agg_f32(const float* __restrict__ h,
                                                 const int* __restrict__ rowptr,
                                                 const int* __restrict__ csr,
                                                 const float* __restrict__ inv_denom,
                                                 float* __restrict__ agg, int n) {
  int gw = (int)((blockIdx.x * 256u + threadIdx.x) >> 6);
  if (gw >= n) return;
  int lane = threadIdx.x & 63;
  int half = lane >> 5, sub = lane & 31;
  int beg = __builtin_amdgcn_readfirstlane(rowptr[gw]);
  int end = __builtin_amdgcn_readfirstlane(rowptr[gw + 1]);
  float sx0 = 0.f, sy0 = 0.f, sz0 = 0.f, sw0 = 0.f;
  float sx1 = 0.f, sy1 = 0.f, sz1 = 0.f, sw1 = 0.f;
  int e = beg;
  for (; e + 4 <= end; e += 4) {
    int i0 = csr[e + half];
    int i1 = csr[e + 2 + half];
    float4 v0 = ((const float4*)(h + (size_t)i0 * D))[sub];
    float4 v1 = ((const float4*)(h + (size_t)i1 * D))[sub];
    sx0 += v0.x; sy0 += v0.y; sz0 += v0.z; sw0 += v0.w;
    sx1 += v1.x; sy1 += v1.y; sz1 += v1.z; sw1 += v1.w;
  }
  if (e + 2 <= end) {
    int i0 = csr[e + half];
    float4 v0 = ((const float4*)(h + (size_t)i0 * D))[sub];
    sx0 += v0.x; sy0 += v0.y; sz0 += v0.z; sw0 += v0.w;
    e += 2;
  }
  if (e < end) {
    int i0 = csr[e];
    float4 v0 = ((const float4*)(h + (size_t)i0 * D))[sub];
    if (half == 0) { sx0 += v0.x; sy0 += v0.y; sz0 += v0.z; sw0 += v0.w; }
  }
  float sx = sx0 + sx1, sy = sy0 + sy1, sz = sz0 + sz1, sw = sw0 + sw1;
  sx += __shfl_xor(sx, 32); sy += __shfl_xor(sy, 32);
  sz += __shfl_xor(sz, 32); sw += __shfl_xor(sw, 32);
  if (half == 0) {
    float iv = inv_denom[gw];
    float4 r; r.x = sx * iv; r.y = sy * iv; r.z = sz * iv; r.w = sw * iv;
    ((float4*)(agg + (size_t)gw * D))[sub] = r;
  }
}

__global__ __launch_bounds__(512) void k_fgemm_f32(const float* A, const float* H,
                                                   const short* __restrict__ WTl,
                                                   const short* __restrict__ WTr,
                                                   const float* __restrict__ bias,
                                                   float* out, int n) {
  __shared__ short wl[WPANEL];
  __shared__ short wr[WPANEL];
  int tid = threadIdx.x;
  for (int i = tid; i < WPANEL / 8; i += 512) {
    ((int4*)wl)[i] = ((const int4*)WTl)[i];
    ((int4*)wr)[i] = ((const int4*)WTr)[i];
  }
  __syncthreads();
  int lane = tid & 63, wid = tid >> 6;
  int c = lane & 15, g = lane >> 4;
  float bv[8];
#pragma unroll
  for (int cc = 0; cc < 8; ++cc) bv[cc] = bias[cc * 16 + c];
  int ntile = (n + 15) >> 4;
  for (int tile = blockIdx.x * 8 + wid; tile < ntile; tile += gridDim.x * 8) {
    int r0 = tile * 16;
    int row = r0 + c;
    bool rok = row < n;
    f32x4 acc[8];
#pragma unroll
    for (int cc = 0; cc < 8; ++cc) acc[cc] = (f32x4){0.f, 0.f, 0.f, 0.f};
#pragma unroll
    for (int t = 0; t < 4; ++t) {
      short8v af = (short8v){0,0,0,0,0,0,0,0};
      short8v hf = (short8v){0,0,0,0,0,0,0,0};
      if (rok) {
        const float4* pa = (const float4*)(A + (size_t)row * D + t * 32 + g * 8);
        float4 a0 = pa[0], a1 = pa[1];
        const float4* ph = (const float4*)(H + (size_t)row * D + t * 32 + g * 8);
        float4 h0 = ph[0], h1 = ph[1];
        af[0] = (short)f2bf(a0.x); af[1] = (short)f2bf(a0.y); af[2] = (short)f2bf(a0.z); af[3] = (short)f2bf(a0.w);
        af[4] = (short)f2bf(a1.x); af[5] = (short)f2bf(a1.y); af[6] = (short)f2bf(a1.z); af[7] = (short)f2bf(a1.w);
        hf[0] = (short)f2bf(h0.x); hf[1] = (short)f2bf(h0.y); hf[2] = (short)f2bf(h0.z); hf[3] = (short)f2bf(h0.w);
        hf[4] = (short)f2bf(h1.x); hf[5] = (short)f2bf(h1.y); hf[6] = (short)f2bf(h1.z); hf[7] = (short)f2bf(h1.w);
      }
      int kb = t * 32 + g * 8;
#pragma unroll
      for (int cc = 0; cc < 8; ++cc) {
        short8v bl = *(const short8v*)&wl[(cc * 16 + c) * WSTRIDE + kb];
        acc[cc] = __builtin_amdgcn_mfma_f32_16x16x32_bf16(af, bl, acc[cc], 0, 0, 0);
        short8v br = *(const short8v*)&wr[(cc * 16 + c) * WSTRIDE + kb];
        acc[cc] = __builtin_amdgcn_mfma_f32_16x16x32_bf16(hf, br, acc[cc], 0, 0, 0);
      }
    }
#pragma unroll
    for (int cc = 0; cc < 8; ++cc) {
#pragma unroll
      for (int i = 0; i < 4; ++i) {
        int rr = r0 + g * 4 + i;
        if (rr < n) {
          float o = acc[cc][i] + bv[cc];
          out[(size_t)rr * D + cc * 16 + c] = o > 0.f ? o : 0.f;
        }
      }
    }
  }
}

// ---- launch ----------------------------------------------------------------

extern "C" void kernel_launch(void* const* d_in, const int* in_sizes, int n_in,
                              void* d_out, int out_size, void* d_ws, size_t ws_size,
                              hipStream_t stream) {
  const float* x   = (const float*)d_in[0];
  const int*   ei  = (const int*)d_in[1];
  const float* Wl0 = (const float*)d_in[2];
  const float* Wr0 = (const float*)d_in[3];
  const float* b0  = (const float*)d_in[4];
  const float* Wl1 = (const float*)d_in[5];
  const float* Wr1 = (const float*)d_in[6];
  const float* b1  = (const float*)d_in[7];
  const int N = in_sizes[0] / D;
  const int E = in_sizes[1] / 2;
  float* out = (float*)d_out;

  size_t NP = ((size_t)N + 64) & ~(size_t)63;
  size_t EP = ((size_t)E + 63) & ~(size_t)63;
  const int NBUCK = (N + 511) >> 9;
  const int npi = (int)NP;

  int* W = (int*)d_ws;
  size_t off = 0;
  int*   rowptr = W + off; off += NP;
  int*   cnt    = W + off; off += NP;
  float* inv    = (float*)(W + off); off += NP;
  int*   bsum   = W + off; off += 1024;
  int*   gcur   = W + off; off += 256;
  int*   csr    = W + off; off += EP;
  short* wt     = (short*)(W + off); off += (size_t)4 * WPANEL / 2;   // fallback layout
  short* wf     = (short*)(W + off); off += (size_t)4 * (D * D) / 2;  // frag layout
  size_t base = off;
  short* aggb = (short*)(W + off); off += NP * 64;   // sliced [8][NP][16]
  short* xb   = (short*)(W + off); off += NP * 64;   // sliced
  short* h1b  = (short*)(W + off); off += NP * 64;   // sliced
  size_t need_new = off * 4;
  float* aggf = (float*)(W + base);                  // fallback fp32 agg buffer
  bool use_bf = ws_size >= need_new;
  int* gbuf = use_bf ? (int*)xb : (int*)aggf;        // overlay: consumed pre-agg

  hipMemsetAsync(gcur, 0, 256 * sizeof(int), stream);

  int NB = (N + 1023) / 1024;
  k_bin<<<(E + 2047) / 2048, 256, 0, stream>>>(ei, E, gcur, gbuf);
  k_hist<<<NBUCK, 256, 0, stream>>>(gcur, gbuf, cnt, N);
  k_scan1<<<NB, 1024, 0, stream>>>(cnt, N, rowptr, inv, bsum);
  k_scan2<<<1, 64, 0, stream>>>(bsum, NB, rowptr, N);
  k_scan3<<<NB, 1024, 0, stream>>>(rowptr, bsum, N);
  k_place<<<NBUCK, 256, 0, stream>>>(gcur, gbuf, rowptr, csr, N);

  dim3 wgrid((D * D + 255) / 256, 4);

  if (use_bf) {
    k_wprep_frag<<<wgrid, 256, 0, stream>>>(Wl0, Wr0, Wl1, Wr1, wf);
    k_tobf16_sl<<<(N * 16 + 255) / 256, 256, 0, stream>>>(x, xb, N, npi);

    int agrid = ((N + 15) / 16) * 8;     // slice = bid % 8 -> XCD-pinned
    int nt32 = (N + 31) >> 5;
    int ggrid = (nt32 + 3) / 4;
    // layer 0
    k_agg_sl<<<agrid, 256, 0, stream>>>(xb, rowptr, csr, inv, aggb, N, npi);
    k_fgemm_bf<0><<<ggrid, 256, 0, stream>>>(aggb, xb, wf, wf + D * D, b0, h1b, N, npi);
    // layer 1
    k_agg_sl<<<agrid, 256, 0, stream>>>(h1b, rowptr, csr, inv, aggb, N, npi);
    k_fgemm_bf<1><<<ggrid, 256, 0, stream>>>(aggb, h1b, wf + 2 * D * D, wf + 3 * D * D, b1, out, N, npi);
  } else {
    // fp32 fallback (proven footprint)
    int agrid = (N + 3) / 4;
    k_wprep<<<wgrid, 256, 0, stream>>>(Wl0, Wr0, Wl1, Wr1, wt);
    k_agg_f32<<<agrid, 256, 0, stream>>>(x, rowptr, csr, inv, aggf, N);
    k_fgemm_f32<<<512, 512, 0, stream>>>(aggf, x, wt, wt + WPANEL, b0, out, N);
    k_agg_f32<<<agrid, 256, 0, stream>>>(out, rowptr, csr, inv, aggf, N);
    k_fgemm_f32<<<512, 512, 0, stream>>>(aggf, out, wt + 2 * WPANEL, wt + 3 * WPANEL, b1, out, N);
  }
}

// Round 11
// 263.512 us; speedup vs baseline: 1.3754x; 1.3754x over previous
//
#include <hip/hip_runtime.h>
#include <hip/hip_bf16.h>

// GraphSAGE backbone: 2x SAGEConv(mean), N=100000, E=1600000, D=128, fp32 in/out.
// CSR build via 2-pass bucket binning (k_bin itself two-pass: count, place).
// Per layer: agg = mean gather (LINEAR 256-B bf16 rows, fp32 accum via
// v_dot2_f32_bf16); out = relu(agg@Wl + h@Wr + b) fused bf16 MFMA GEMM,
// NO LDS: weights pre-swizzled fragment-major, streamed from L2.
// NOTE (R10 lesson): column-slicing rows below 64 B breaks cache-line
// granularity on the random gather and doubles L2/L1 request traffic.

#define D 128
#define WSTRIDE 136            // fallback path only
#define WPANEL (D * WSTRIDE)
#define GCAP 12288             // per-bucket capacity (mean ~8166)
#define BPB 8192               // edges per k_bin block

typedef __attribute__((ext_vector_type(8))) short short8v;
typedef __attribute__((ext_vector_type(4))) float f32x4;

__device__ inline unsigned short f2bf(float f) {   // fp32 -> bf16 RNE
  unsigned u = __float_as_uint(f);
  return (unsigned short)((u + 0x7FFFu + ((u >> 16) & 1u)) >> 16);
}
__device__ inline unsigned pack2(float lo, float hi) {
  return (unsigned)f2bf(lo) | ((unsigned)f2bf(hi) << 16);
}

// acc += lo_bf16(u) : src1 = {1.0bf16, 0} = 0x00003F80 (SGPR)
__device__ inline void dot2lo(unsigned u, float& a) {
  asm("v_dot2_f32_bf16 %0, %1, %2, %0" : "+v"(a) : "v"(u), "s"(0x00003F80u));
}
// acc += hi_bf16(u) : src1 = {0, 1.0bf16} = 0x3F800000 = inline const 1.0
__device__ inline void dot2hi(unsigned u, float& a) {
  asm("v_dot2_f32_bf16 %0, %1, 1.0, %0" : "+v"(a) : "v"(u));
}

// ---- pass A: bin edges by dst>>9 into gbuf[b*GCAP + cursor] ----------------
// Two-pass per block (8192 edges): count -> one global atomic per bucket ->
// re-read and place. Long runs (~42 entries) per bucket per block give
// near-full-line gbuf writes.

__global__ __launch_bounds__(256) void k_bin(const int* __restrict__ ei, int E,
                                             int* __restrict__ gcur,
                                             int* __restrict__ gbuf) {
  __shared__ int hcnt[256], hbase[256], hfill[256];
  int tid = threadIdx.x;
  hcnt[tid] = 0;
  __syncthreads();
  int e0 = blockIdx.x * BPB;
#pragma unroll
  for (int it = 0; it < BPB / 256; ++it) {
    int e = e0 + it * 256 + tid;
    if (e < E) atomicAdd(&hcnt[ei[E + e] >> 9], 1);
  }
  __syncthreads();
  int c = hcnt[tid];
  hbase[tid] = c ? atomicAdd(&gcur[tid], c) : 0;
  hfill[tid] = 0;
  __syncthreads();
#pragma unroll
  for (int it = 0; it < BPB / 256; ++it) {
    int e = e0 + it * 256 + tid;
    if (e < E) {
      int s = ei[e], d = ei[E + e];
      int bk = d >> 9;
      int slot = atomicAdd(&hfill[bk], 1);
      gbuf[(size_t)bk * GCAP + hbase[bk] + slot] = (s << 9) | (d & 511);
    }
  }
}

// ---- pass B1: per-bucket degree histogram -> cnt (coalesced) ---------------

__global__ __launch_bounds__(256) void k_hist(const int* __restrict__ gcur,
                                              const int* __restrict__ gbuf,
                                              int* __restrict__ cnt, int n) {
  __shared__ int hc[512];
  int b = blockIdx.x, tid = threadIdx.x;
  hc[tid] = 0; hc[tid + 256] = 0;
  __syncthreads();
  int m = gcur[b];
  for (int i = tid; i < m; i += 256)
    atomicAdd(&hc[gbuf[(size_t)b * GCAP + i] & 511], 1);
  __syncthreads();
#pragma unroll
  for (int k = 0; k < 2; ++k) {
    int i = k * 256 + tid, node = b * 512 + i;
    if (node < n) cnt[node] = hc[i];
  }
}

// ---- hierarchical exclusive scan: cnt -> rowptr, plus inv_denom ------------

__global__ __launch_bounds__(1024) void k_scan1(const int* __restrict__ cnt, int n,
                                                int* __restrict__ rowptr,
                                                float* __restrict__ inv_denom,
                                                int* __restrict__ bsum) {
  __shared__ int wsum[16];
  int tid = threadIdx.x, lane = tid & 63, wid = tid >> 6;
  int i = blockIdx.x * 1024 + tid;
  int v = (i < n) ? cnt[i] : 0;
  int x = v;
#pragma unroll
  for (int off = 1; off < 64; off <<= 1) {
    int t = __shfl_up(x, (unsigned)off);
    if (lane >= off) x += t;
  }
  if (lane == 63) wsum[wid] = x;
  __syncthreads();
  if (tid < 16) {
    int w = wsum[tid], y = w;
#pragma unroll
    for (int off = 1; off < 16; off <<= 1) {
      int t = __shfl_up(y, (unsigned)off);
      if (tid >= off) y += t;
    }
    wsum[tid] = y - w;   // exclusive
  }
  __syncthreads();
  if (i < n) {
    rowptr[i] = wsum[wid] + x - v;
    inv_denom[i] = 1.0f / (float)((v > 1) ? v : 1);
  }
  if (tid == 1023) bsum[blockIdx.x] = wsum[15] + x;
}

__global__ __launch_bounds__(64) void k_scan2(int* __restrict__ bsum, int nb,
                                              int* __restrict__ rowptr, int n) {
  int lane = threadIdx.x;
  int v0 = (lane < nb) ? bsum[lane] : 0;
  int v1 = (64 + lane < nb) ? bsum[64 + lane] : 0;
  int x = v0;
#pragma unroll
  for (int off = 1; off < 64; off <<= 1) {
    int t = __shfl_up(x, (unsigned)off);
    if (lane >= off) x += t;
  }
  int tot0 = __shfl(x, 63);
  int y = v1;
#pragma unroll
  for (int off = 1; off < 64; off <<= 1) {
    int t = __shfl_up(y, (unsigned)off);
    if (lane >= off) y += t;
  }
  if (lane < nb) bsum[lane] = x - v0;
  if (64 + lane < nb) bsum[64 + lane] = tot0 + (y - v1);
  if (lane == 63) rowptr[n] = tot0 + y;
}

__global__ __launch_bounds__(1024) void k_scan3(int* __restrict__ rowptr,
                                                const int* __restrict__ bsum, int n) {
  int i = blockIdx.x * 1024 + threadIdx.x;
  if (i < n) rowptr[i] += bsum[blockIdx.x];
}

// ---- pass B2: place entries into csr (one bucket = one block) --------------

__global__ __launch_bounds__(256) void k_place(const int* __restrict__ gcur,
                                               const int* __restrict__ gbuf,
                                               const int* __restrict__ rowptr,
                                               int* __restrict__ csr, int n) {
  __shared__ int rp[512], hf[512];
  int b = blockIdx.x, tid = threadIdx.x;
#pragma unroll
  for (int k = 0; k < 2; ++k) {
    int i = k * 256 + tid, node = b * 512 + i;
    rp[i] = (node < n) ? rowptr[node] : 0;
    hf[i] = 0;
  }
  __syncthreads();
  int m = gcur[b];
  for (int i = tid; i < m; i += 256) {
    int ent = gbuf[(size_t)b * GCAP + i];
    int d = ent & 511, s = ent >> 9;
    csr[rp[d] + atomicAdd(&hf[d], 1)] = s;
  }
}

// ---- fp32 -> bf16 row conversion (linear layout) ---------------------------

__global__ __launch_bounds__(256) void k_tobf16(const float* __restrict__ in,
                                                short* __restrict__ ob, long long ng) {
  long long i = (long long)blockIdx.x * 256 + threadIdx.x;   // groups of 8 floats
  if (i >= ng) return;
  const float4* p = (const float4*)in + i * 2;
  float4 a = p[0], b = p[1];
  uint4 o;
  o.x = pack2(a.x, a.y); o.y = pack2(a.z, a.w);
  o.z = pack2(b.x, b.y); o.w = pack2(b.z, b.w);
  ((uint4*)ob)[i] = o;
}

// ---- weight prep (fragment-major): WF[((t*8+cc)*64+l)*8+j] =
//        bf16( W[t*32 + (l>>4)*8 + j][cc*16 + (l&15)] )  -------------------

__global__ __launch_bounds__(256) void k_wprep_frag(const float* __restrict__ W0,
                                                    const float* __restrict__ W1,
                                                    const float* __restrict__ W2,
                                                    const float* __restrict__ W3,
                                                    short* __restrict__ WF) {
  const float* W = (blockIdx.y == 0) ? W0 : (blockIdx.y == 1) ? W1
                 : (blockIdx.y == 2) ? W2 : W3;
  short* o = WF + (size_t)blockIdx.y * (D * D);
  int i = blockIdx.x * 256 + threadIdx.x;
  if (i < D * D) {
    int j = i & 7, l = (i >> 3) & 63, cc = (i >> 9) & 7, t = i >> 12;
    int k = t * 32 + (l >> 4) * 8 + j;
    int c = cc * 16 + (l & 15);
    o[i] = (short)f2bf(W[k * D + c]);
  }
}

// ---- weight prep (padded-transpose, fallback path only) --------------------

__global__ __launch_bounds__(256) void k_wprep(const float* __restrict__ W0,
                                               const float* __restrict__ W1,
                                               const float* __restrict__ W2,
                                               const float* __restrict__ W3,
                                               short* __restrict__ WT) {
  const float* W = (blockIdx.y == 0) ? W0 : (blockIdx.y == 1) ? W1
                 : (blockIdx.y == 2) ? W2 : W3;
  short* o = WT + (size_t)blockIdx.y * WPANEL;
  int i = blockIdx.x * 256 + threadIdx.x;
  if (i < D * D) {
    int k = i >> 7, c = i & 127;
    o[c * WSTRIDE + k] = (short)f2bf(W[i]);
  }
}

// ---- bf16 mean aggregation: wave/node, 16-lane quarters, 4-deep MLP,
//      bf16->fp32 accumulate via v_dot2_f32_bf16 (1 instr per element) -------

__global__ __launch_bounds__(256) void k_agg_bf(const short* __restrict__ hb,
                                                const int* __restrict__ rowptr,
                                                const int* __restrict__ csr,
                                                const float* __restrict__ inv_denom,
                                                short* __restrict__ agg, int n) {
  int gw = (int)((blockIdx.x * 256u + threadIdx.x) >> 6);
  if (gw >= n) return;
  int lane = threadIdx.x & 63;
  int q = lane >> 4, s16 = lane & 15;
  int beg = __builtin_amdgcn_readfirstlane(rowptr[gw]);
  int end = __builtin_amdgcn_readfirstlane(rowptr[gw + 1]);
  float a0 = 0.f, a1 = 0.f, a2 = 0.f, a3 = 0.f;
  float a4 = 0.f, a5 = 0.f, a6 = 0.f, a7 = 0.f;
  auto addrow = [&](uint4 v) {
    dot2lo(v.x, a0); dot2hi(v.x, a1);
    dot2lo(v.y, a2); dot2hi(v.y, a3);
    dot2lo(v.z, a4); dot2hi(v.z, a5);
    dot2lo(v.w, a6); dot2hi(v.w, a7);
  };
  int e = beg + q;
  for (; e + 12 < end; e += 16) {   // 4 edges in flight per quarter
    int s0 = csr[e], s1 = csr[e + 4], s2 = csr[e + 8], s3 = csr[e + 12];
    uint4 v0 = ((const uint4*)(hb + (size_t)s0 * D))[s16];
    uint4 v1 = ((const uint4*)(hb + (size_t)s1 * D))[s16];
    uint4 v2 = ((const uint4*)(hb + (size_t)s2 * D))[s16];
    uint4 v3 = ((const uint4*)(hb + (size_t)s3 * D))[s16];
    addrow(v0); addrow(v1); addrow(v2); addrow(v3);
  }
  for (; e + 4 < end; e += 8) {     // 2-deep tail
    int s0 = csr[e], s1 = csr[e + 4];
    uint4 v0 = ((const uint4*)(hb + (size_t)s0 * D))[s16];
    uint4 v1 = ((const uint4*)(hb + (size_t)s1 * D))[s16];
    addrow(v0); addrow(v1);
  }
  if (e < end) {
    int s0 = csr[e];
    uint4 v0 = ((const uint4*)(hb + (size_t)s0 * D))[s16];
    addrow(v0);
  }
  a0 += __shfl_xor(a0, 16); a0 += __shfl_xor(a0, 32);
  a1 += __shfl_xor(a1, 16); a1 += __shfl_xor(a1, 32);
  a2 += __shfl_xor(a2, 16); a2 += __shfl_xor(a2, 32);
  a3 += __shfl_xor(a3, 16); a3 += __shfl_xor(a3, 32);
  a4 += __shfl_xor(a4, 16); a4 += __shfl_xor(a4, 32);
  a5 += __shfl_xor(a5, 16); a5 += __shfl_xor(a5, 32);
  a6 += __shfl_xor(a6, 16); a6 += __shfl_xor(a6, 32);
  a7 += __shfl_xor(a7, 16); a7 += __shfl_xor(a7, 32);
  if (q == 0) {
    float iv = inv_denom[gw];
    uint4 o;
    o.x = pack2(a0 * iv, a1 * iv);
    o.y = pack2(a2 * iv, a3 * iv);
    o.z = pack2(a4 * iv, a5 * iv);
    o.w = pack2(a6 * iv, a7 * iv);
    ((uint4*)(agg + (size_t)gw * D))[s16] = o;
  }
}

// ---- fused layer GEMM, NO LDS: out = relu(A@Wl + H@Wr + b) -----------------
// Wave owns a 32-row tile (two 16-row halves share each B-fragment).
// B-fragments loaded fragment-major from global (L2-resident, coalesced).
// OUTF=0: bf16 out; OUTF=1: fp32 out.

template <int OUTF>
__global__ __launch_bounds__(256) void k_fgemm_bf(const short* __restrict__ A,
                                                  const short* __restrict__ H,
                                                  const short* __restrict__ WFl,
                                                  const short* __restrict__ WFr,
                                                  const float* __restrict__ bias,
                                                  void* __restrict__ outv, int n) {
  int tid = threadIdx.x;
  int lane = tid & 63, w4 = tid >> 6;
  int nt = (n + 31) >> 5;
  int wtile = blockIdx.x * 4 + w4;
  if (wtile >= nt) return;
  int c = lane & 15, g = lane >> 4;
  int r0 = wtile * 32;
  int row0 = r0 + c, row1 = r0 + 16 + c;
  bool ok0 = row0 < n, ok1 = row1 < n;

  float bv[8];
#pragma unroll
  for (int cc = 0; cc < 8; ++cc) bv[cc] = bias[cc * 16 + c];

  const short8v* Fl = (const short8v*)WFl;
  const short8v* Fr = (const short8v*)WFr;

  f32x4 acc0[8], acc1[8];
#pragma unroll
  for (int cc = 0; cc < 8; ++cc) {
    acc0[cc] = (f32x4){0.f, 0.f, 0.f, 0.f};
    acc1[cc] = (f32x4){0.f, 0.f, 0.f, 0.f};
  }

#pragma unroll
  for (int t = 0; t < 4; ++t) {
    short8v a0 = (short8v){0,0,0,0,0,0,0,0}, h0 = a0, a1 = a0, h1 = a0;
    int kb = t * 32 + g * 8;
    if (ok0) {
      a0 = *(const short8v*)(A + (size_t)row0 * D + kb);
      h0 = *(const short8v*)(H + (size_t)row0 * D + kb);
    }
    if (ok1) {
      a1 = *(const short8v*)(A + (size_t)row1 * D + kb);
      h1 = *(const short8v*)(H + (size_t)row1 * D + kb);
    }
#pragma unroll
    for (int cc = 0; cc < 8; ++cc) {
      short8v bl = Fl[(t * 8 + cc) * 64 + lane];
      short8v br = Fr[(t * 8 + cc) * 64 + lane];
      acc0[cc] = __builtin_amdgcn_mfma_f32_16x16x32_bf16(a0, bl, acc0[cc], 0, 0, 0);
      acc0[cc] = __builtin_amdgcn_mfma_f32_16x16x32_bf16(h0, br, acc0[cc], 0, 0, 0);
      acc1[cc] = __builtin_amdgcn_mfma_f32_16x16x32_bf16(a1, bl, acc1[cc], 0, 0, 0);
      acc1[cc] = __builtin_amdgcn_mfma_f32_16x16x32_bf16(h1, br, acc1[cc], 0, 0, 0);
    }
  }

#pragma unroll
  for (int cc = 0; cc < 8; ++cc) {
#pragma unroll
    for (int i = 0; i < 4; ++i) {
      int rr0 = r0 + g * 4 + i;
      int rr1 = rr0 + 16;
      float o0 = acc0[cc][i] + bv[cc];
      float o1 = acc1[cc][i] + bv[cc];
      o0 = o0 > 0.f ? o0 : 0.f;
      o1 = o1 > 0.f ? o1 : 0.f;
      if (OUTF) {
        if (rr0 < n) ((float*)outv)[(size_t)rr0 * D + cc * 16 + c] = o0;
        if (rr1 < n) ((float*)outv)[(size_t)rr1 * D + cc * 16 + c] = o1;
      } else {
        if (rr0 < n) ((short*)outv)[(size_t)rr0 * D + cc * 16 + c] = (short)f2bf(o0);
        if (rr1 < n) ((short*)outv)[(size_t)rr1 * D + cc * 16 + c] = (short)f2bf(o1);
      }
    }
  }
}

// ---- fp32 fallback kernels (used only if ws_size is too small) -------------

__global__ __launch_bounds__(256) void k_agg_f32(const float* __restrict__ h,
                                                 const int* __restrict__ rowptr,
                                                 const int* __restrict__ csr,
                                                 const float* __restrict__ inv_denom,
                                                 float* __restrict__ agg, int n) {
  int gw = (int)((blockIdx.x * 256u + threadIdx.x) >> 6);
  if (gw >= n) return;
  int lane = threadIdx.x & 63;
  int half = lane >> 5, sub = lane & 31;
  int beg = __builtin_amdgcn_readfirstlane(rowptr[gw]);
  int end = __builtin_amdgcn_readfirstlane(rowptr[gw + 1]);
  float sx0 = 0.f, sy0 = 0.f, sz0 = 0.f, sw0 = 0.f;
  float sx1 = 0.f, sy1 = 0.f, sz1 = 0.f, sw1 = 0.f;
  int e = beg;
  for (; e + 4 <= end; e += 4) {
    int i0 = csr[e + half];
    int i1 = csr[e + 2 + half];
    float4 v0 = ((const float4*)(h + (size_t)i0 * D))[sub];
    float4 v1 = ((const float4*)(h + (size_t)i1 * D))[sub];
    sx0 += v0.x; sy0 += v0.y; sz0 += v0.z; sw0 += v0.w;
    sx1 += v1.x; sy1 += v1.y; sz1 += v1.z; sw1 += v1.w;
  }
  if (e + 2 <= end) {
    int i0 = csr[e + half];
    float4 v0 = ((const float4*)(h + (size_t)i0 * D))[sub];
    sx0 += v0.x; sy0 += v0.y; sz0 += v0.z; sw0 += v0.w;
    e += 2;
  }
  if (e < end) {
    int i0 = csr[e];
    float4 v0 = ((const float4*)(h + (size_t)i0 * D))[sub];
    if (half == 0) { sx0 += v0.x; sy0 += v0.y; sz0 += v0.z; sw0 += v0.w; }
  }
  float sx = sx0 + sx1, sy = sy0 + sy1, sz = sz0 + sz1, sw = sw0 + sw1;
  sx += __shfl_xor(sx, 32); sy += __shfl_xor(sy, 32);
  sz += __shfl_xor(sz, 32); sw += __shfl_xor(sw, 32);
  if (half == 0) {
    float iv = inv_denom[gw];
    float4 r; r.x = sx * iv; r.y = sy * iv; r.z = sz * iv; r.w = sw * iv;
    ((float4*)(agg + (size_t)gw * D))[sub] = r;
  }
}

__global__ __launch_bounds__(512) void k_fgemm_f32(const float* A, const float* H,
                                                   const short* __restrict__ WTl,
                                                   const short* __restrict__ WTr,
                                                   const float* __restrict__ bias,
                                                   float* out, int n) {
  __shared__ short wl[WPANEL];
  __shared__ short wr[WPANEL];
  int tid = threadIdx.x;
  for (int i = tid; i < WPANEL / 8; i += 512) {
    ((int4*)wl)[i] = ((const int4*)WTl)[i];
    ((int4*)wr)[i] = ((const int4*)WTr)[i];
  }
  __syncthreads();
  int lane = tid & 63, wid = tid >> 6;
  int c = lane & 15, g = lane >> 4;
  float bv[8];
#pragma unroll
  for (int cc = 0; cc < 8; ++cc) bv[cc] = bias[cc * 16 + c];
  int ntile = (n + 15) >> 4;
  for (int tile = blockIdx.x * 8 + wid; tile < ntile; tile += gridDim.x * 8) {
    int r0 = tile * 16;
    int row = r0 + c;
    bool rok = row < n;
    f32x4 acc[8];
#pragma unroll
    for (int cc = 0; cc < 8; ++cc) acc[cc] = (f32x4){0.f, 0.f, 0.f, 0.f};
#pragma unroll
    for (int t = 0; t < 4; ++t) {
      short8v af = (short8v){0,0,0,0,0,0,0,0};
      short8v hf = (short8v){0,0,0,0,0,0,0,0};
      if (rok) {
        const float4* pa = (const float4*)(A + (size_t)row * D + t * 32 + g * 8);
        float4 a0 = pa[0], a1 = pa[1];
        const float4* ph = (const float4*)(H + (size_t)row * D + t * 32 + g * 8);
        float4 h0 = ph[0], h1 = ph[1];
        af[0] = (short)f2bf(a0.x); af[1] = (short)f2bf(a0.y); af[2] = (short)f2bf(a0.z); af[3] = (short)f2bf(a0.w);
        af[4] = (short)f2bf(a1.x); af[5] = (short)f2bf(a1.y); af[6] = (short)f2bf(a1.z); af[7] = (short)f2bf(a1.w);
        hf[0] = (short)f2bf(h0.x); hf[1] = (short)f2bf(h0.y); hf[2] = (short)f2bf(h0.z); hf[3] = (short)f2bf(h0.w);
        hf[4] = (short)f2bf(h1.x); hf[5] = (short)f2bf(h1.y); hf[6] = (short)f2bf(h1.z); hf[7] = (short)f2bf(h1.w);
      }
      int kb = t * 32 + g * 8;
#pragma unroll
      for (int cc = 0; cc < 8; ++cc) {
        short8v bl = *(const short8v*)&wl[(cc * 16 + c) * WSTRIDE + kb];
        acc[cc] = __builtin_amdgcn_mfma_f32_16x16x32_bf16(af, bl, acc[cc], 0, 0, 0);
        short8v br = *(const short8v*)&wr[(cc * 16 + c) * WSTRIDE + kb];
        acc[cc] = __builtin_amdgcn_mfma_f32_16x16x32_bf16(hf, br, acc[cc], 0, 0, 0);
      }
    }
#pragma unroll
    for (int cc = 0; cc < 8; ++cc) {
#pragma unroll
      for (int i = 0; i < 4; ++i) {
        int rr = r0 + g * 4 + i;
        if (rr < n) {
          float o = acc[cc][i] + bv[cc];
          out[(size_t)rr * D + cc * 16 + c] = o > 0.f ? o : 0.f;
        }
      }
    }
  }
}

// ---- launch ----------------------------------------------------------------

extern "C" void kernel_launch(void* const* d_in, const int* in_sizes, int n_in,
                              void* d_out, int out_size, void* d_ws, size_t ws_size,
                              hipStream_t stream) {
  const float* x   = (const float*)d_in[0];
  const int*   ei  = (const int*)d_in[1];
  const float* Wl0 = (const float*)d_in[2];
  const float* Wr0 = (const float*)d_in[3];
  const float* b0  = (const float*)d_in[4];
  const float* Wl1 = (const float*)d_in[5];
  const float* Wr1 = (const float*)d_in[6];
  const float* b1  = (const float*)d_in[7];
  const int N = in_sizes[0] / D;
  const int E = in_sizes[1] / 2;
  float* out = (float*)d_out;

  size_t NP = ((size_t)N + 64) & ~(size_t)63;
  size_t EP = ((size_t)E + 63) & ~(size_t)63;
  const int NBUCK = (N + 511) >> 9;

  int* W = (int*)d_ws;
  size_t off = 0;
  int*   rowptr = W + off; off += NP;
  int*   cnt    = W + off; off += NP;
  float* inv    = (float*)(W + off); off += NP;
  int*   bsum   = W + off; off += 1024;
  int*   gcur   = W + off; off += 256;
  int*   csr    = W + off; off += EP;
  short* wt     = (short*)(W + off); off += (size_t)4 * WPANEL / 2;   // fallback layout
  short* wf     = (short*)(W + off); off += (size_t)4 * (D * D) / 2;  // frag layout
  size_t base = off;
  short* aggb = (short*)(W + off); off += NP * 64;
  short* xb   = (short*)(W + off); off += NP * 64;
  short* h1b  = (short*)(W + off); off += NP * 64;
  size_t need_new = off * 4;
  float* aggf = (float*)(W + base);                 // fallback fp32 agg buffer
  bool use_bf = ws_size >= need_new;
  int* gbuf = use_bf ? (int*)xb : (int*)aggf;       // overlay: consumed pre-agg

  hipMemsetAsync(gcur, 0, 256 * sizeof(int), stream);

  int NB = (N + 1023) / 1024;
  k_bin<<<(E + BPB - 1) / BPB, 256, 0, stream>>>(ei, E, gcur, gbuf);
  k_hist<<<NBUCK, 256, 0, stream>>>(gcur, gbuf, cnt, N);
  k_scan1<<<NB, 1024, 0, stream>>>(cnt, N, rowptr, inv, bsum);
  k_scan2<<<1, 64, 0, stream>>>(bsum, NB, rowptr, N);
  k_scan3<<<NB, 1024, 0, stream>>>(rowptr, bsum, N);
  k_place<<<NBUCK, 256, 0, stream>>>(gcur, gbuf, rowptr, csr, N);

  int agrid = (N + 3) / 4;
  dim3 wgrid((D * D + 255) / 256, 4);

  if (use_bf) {
    k_wprep_frag<<<wgrid, 256, 0, stream>>>(Wl0, Wr0, Wl1, Wr1, wf);
    long long ng = (long long)N * (D / 8);
    k_tobf16<<<(int)((ng + 255) / 256), 256, 0, stream>>>(x, xb, ng);
    int nt32 = (N + 31) >> 5;
    int ggrid = (nt32 + 3) / 4;
    // layer 0
    k_agg_bf<<<agrid, 256, 0, stream>>>(xb, rowptr, csr, inv, aggb, N);
    k_fgemm_bf<0><<<ggrid, 256, 0, stream>>>(aggb, xb, wf, wf + D * D, b0, h1b, N);
    // layer 1
    k_agg_bf<<<agrid, 256, 0, stream>>>(h1b, rowptr, csr, inv, aggb, N);
    k_fgemm_bf<1><<<ggrid, 256, 0, stream>>>(aggb, h1b, wf + 2 * D * D, wf + 3 * D * D, b1, out, N);
  } else {
    // fp32 fallback (proven footprint)
    k_wprep<<<wgrid, 256, 0, stream>>>(Wl0, Wr0, Wl1, Wr1, wt);
    k_agg_f32<<<agrid, 256, 0, stream>>>(x, rowptr, csr, inv, aggf, N);
    k_fgemm_f32<<<512, 512, 0, stream>>>(aggf, x, wt, wt + WPANEL, b0, out, N);
    k_agg_f32<<<agrid, 256, 0, stream>>>(out, rowptr, csr, inv, aggf, N);
    k_fgemm_f32<<<512, 512, 0, stream>>>(aggf, out, wt + 2 * WPANEL, wt + 3 * WPANEL, b1, out, N);
  }
}